// Round 4
// baseline (2964.181 us; speedup 1.0000x reference)
//
#include <hip/hip_runtime.h>
#include <math.h>

// Problem constants
#define N_ROWS   16384   // B*H*W
#define N_CODES  16384   // N_EMBED
#define K_DIM    256     // EMBED_DIM
#define HW       1024    // 32*32
#define N_ELEMS  4194304 // N_ROWS * K_DIM

// Output layout (floats), concatenated in reference return order
#define OUT_ZQ      0
#define OUT_LOSS    4194304
#define OUT_PERP    4194305
#define OUT_ONEHOT  4194306
#define OUT_IDX     272629762   // 4194306 + 16384*16384

// ws layout (bytes)
#define WS_LOSS    0        // double
#define WS_HIST    64       // 16384 u32
#define WS_IDX     65600    // 16384 i32
#define WS_ENORM   131136   // 16384 f32
#define WS_MINVAL  196672   // 8*16384 f32
#define WS_MINIDX  720960   // 8*16384 i32
#define WS_ZNORM   1245248  // 16384 f32  (total 1310784 B)

typedef float floatx2 __attribute__((ext_vector_type(2)));

// ---------------------------------------------------------------------------
// k0: ||z_row||^2 per row, BIT-MATCHING numpy's pairwise summation of the
// rounded temp array zf*zf (n=256 -> two 128-blocks, each with 8 interleaved
// accumulators and the ((r0+r1)+(r2+r3))+((r4+r5)+(r6+r7)) combine).
// The asm guard stops v*v from being FMA-fused into the add (numpy rounds
// the square first). One thread per row; loads coalesce across threads.
__global__ __launch_bounds__(256) void znorm_kernel(
    const float* __restrict__ z, float* __restrict__ znorm)
{
    const int n = blockIdx.x * 256 + threadIdx.x;
    const int b = n >> 10;
    const int sp = n & 1023;
    const float* zr = z + (size_t)b * K_DIM * HW + sp;  // dim c at zr[c*HW]

    float h0, h1;
    {
        float r[8];
        #pragma unroll
        for (int j = 0; j < 8; ++j) {
            float v = zr[(size_t)j * HW];
            float sq = v * v; asm volatile("" : "+v"(sq));
            r[j] = sq;
        }
        for (int i = 8; i < 128; i += 8) {
            #pragma unroll
            for (int j = 0; j < 8; ++j) {
                float v = zr[(size_t)(i + j) * HW];
                float sq = v * v; asm volatile("" : "+v"(sq));
                r[j] += sq;
            }
        }
        h0 = ((r[0] + r[1]) + (r[2] + r[3])) + ((r[4] + r[5]) + (r[6] + r[7]));
    }
    {
        float r[8];
        #pragma unroll
        for (int j = 0; j < 8; ++j) {
            float v = zr[(size_t)(128 + j) * HW];
            float sq = v * v; asm volatile("" : "+v"(sq));
            r[j] = sq;
        }
        for (int i = 8; i < 128; i += 8) {
            #pragma unroll
            for (int j = 0; j < 8; ++j) {
                float v = zr[(size_t)(128 + i + j) * HW];
                float sq = v * v; asm volatile("" : "+v"(sq));
                r[j] += sq;
            }
        }
        h1 = ((r[0] + r[1]) + (r[2] + r[3])) + ((r[4] + r[5]) + (r[6] + r[7]));
    }
    znorm[n] = h0 + h1;
}

// ---------------------------------------------------------------------------
// k1: ||e_j||^2 per code, same numpy-pairwise bit-match. One thread per code.
__global__ __launch_bounds__(256) void enorm_kernel(
    const float* __restrict__ emb, float* __restrict__ enorm)
{
    const int jc = blockIdx.x * 256 + threadIdx.x;
    const float* er = emb + (size_t)jc * K_DIM;

    float h0, h1;
    {
        float r[8];
        #pragma unroll
        for (int j = 0; j < 8; ++j) {
            float v = er[j];
            float sq = v * v; asm volatile("" : "+v"(sq));
            r[j] = sq;
        }
        for (int i = 8; i < 128; i += 8) {
            #pragma unroll
            for (int j = 0; j < 8; ++j) {
                float v = er[i + j];
                float sq = v * v; asm volatile("" : "+v"(sq));
                r[j] += sq;
            }
        }
        h0 = ((r[0] + r[1]) + (r[2] + r[3])) + ((r[4] + r[5]) + (r[6] + r[7]));
    }
    {
        float r[8];
        #pragma unroll
        for (int j = 0; j < 8; ++j) {
            float v = er[128 + j];
            float sq = v * v; asm volatile("" : "+v"(sq));
            r[j] = sq;
        }
        for (int i = 8; i < 128; i += 8) {
            #pragma unroll
            for (int j = 0; j < 8; ++j) {
                float v = er[128 + i + j];
                float sq = v * v; asm volatile("" : "+v"(sq));
                r[j] += sq;
            }
        }
        h1 = ((r[0] + r[1]) + (r[2] + r[3])) + ((r[4] + r[5]) + (r[6] + r[7]));
    }
    enorm[jc] = h0 + h1;
}

// ---------------------------------------------------------------------------
// k2: fused distance GEMM + running argmin over REFERENCE-QUANTIZED scores
// d = fl(fl(znorm + enorm) - 2*dot). dot accumulates k in ascending order
// with FMA contraction => bitwise-matches OpenBLAS sgemm's in-order FMA
// chain. Ties broken by lowest code index, matching np.argmin.
__global__ __launch_bounds__(256) void gemm_argmin_kernel(
    const float* __restrict__ z, const float* __restrict__ emb,
    const float* __restrict__ enorm, const float* __restrict__ znorm,
    float* __restrict__ minval, int* __restrict__ minidx)
{
    __shared__ float As[16][132];
    __shared__ float Bs[16][132];

    const int rb = blockIdx.x;        // 0..127 row block
    const int cb = blockIdx.y;        // 0..7   code chunk
    const int r0 = rb * 128;
    const int tid = threadIdx.x;
    const int tr = tid >> 4;          // 0..15 (micro-tile row group)
    const int tc = tid & 15;          // 0..15 (micro-tile col group)

    // A staging: thread (ak, ap) loads 8 floats of k-row ak, rows ap*8..+7
    const int ak = tid >> 4;
    const int ap = tid & 15;
    const int bidx = r0 >> 10;        // batch (128 | 1024, never crosses b)
    const int sp0 = r0 & 1023;
    const float* zbase = z + (size_t)bidx * K_DIM * HW + sp0;

    // B staging: thread (bj, bh) loads 8 floats of code c0+bj, dims bh*8..+7
    const int bj = tid >> 1;
    const int bh = tid & 1;

    // per-row ||z||^2 (numpy-bit-matched)
    float zn[8];
    #pragma unroll
    for (int i = 0; i < 8; ++i) zn[i] = znorm[r0 + tr * 8 + i];

    float best[8];
    int   besti[8];
    #pragma unroll
    for (int i = 0; i < 8; ++i) { best[i] = 3.4e38f; besti[i] = 0x7fffffff; }

    for (int t = 0; t < 16; ++t) {
        const int c0 = cb * 2048 + t * 128;

        float acc[8][8];
        #pragma unroll
        for (int i = 0; i < 8; ++i)
            #pragma unroll
            for (int j = 0; j < 8; ++j) acc[i][j] = 0.0f;

        for (int kc = 0; kc < K_DIM; kc += 16) {
            __syncthreads();   // previous iteration's reads complete
            // stage A (z is channel-major: rows contiguous -> coalesced)
            const float* za = zbase + (size_t)(kc + ak) * HW + ap * 8;
            const float4 a0 = *(const float4*)(za);
            const float4 a1 = *(const float4*)(za + 4);
            *(float4*)&As[ak][ap * 8]     = a0;
            *(float4*)&As[ak][ap * 8 + 4] = a1;
            // stage B (transpose 128 codes x 16 dims into Bs[k][code])
            const float* eb = emb + (size_t)(c0 + bj) * K_DIM + kc + bh * 8;
            const float4 b0 = *(const float4*)(eb);
            const float4 b1 = *(const float4*)(eb + 4);
            Bs[bh * 8 + 0][bj] = b0.x;
            Bs[bh * 8 + 1][bj] = b0.y;
            Bs[bh * 8 + 2][bj] = b0.z;
            Bs[bh * 8 + 3][bj] = b0.w;
            Bs[bh * 8 + 4][bj] = b1.x;
            Bs[bh * 8 + 5][bj] = b1.y;
            Bs[bh * 8 + 6][bj] = b1.z;
            Bs[bh * 8 + 7][bj] = b1.w;
            __syncthreads();

            #pragma unroll
            for (int k = 0; k < 16; ++k) {
                float a[8], b[8];
                *(float4*)&a[0] = *(const float4*)&As[k][tr * 8];
                *(float4*)&a[4] = *(const float4*)&As[k][tr * 8 + 4];
                *(float4*)&b[0] = *(const float4*)&Bs[k][tc * 8];
                *(float4*)&b[4] = *(const float4*)&Bs[k][tc * 8 + 4];
                #pragma unroll
                for (int i = 0; i < 8; ++i)
                    #pragma unroll
                    for (int j = 0; j < 8; ++j)
                        acc[i][j] += a[i] * b[j];
            }
        }

        // reference-quantized scores + running argmin (codes ascending per
        // thread; strict < keeps the earliest index, matching np.argmin)
        #pragma unroll
        for (int j = 0; j < 8; ++j) {
            const int code = c0 + tc * 8 + j;
            const float en = enorm[code];
            #pragma unroll
            for (int i = 0; i < 8; ++i) {
                const float tmp = zn[i] + en;         // fl(znorm + enorm)
                const float s = tmp - 2.0f * acc[i][j]; // fl(tmp - 2*dot)
                if (s < best[i]) { best[i] = s; besti[i] = code; }
            }
        }
    }

    // cross-tc reduce: the 16 threads sharing tr are 16 consecutive lanes
    #pragma unroll
    for (int off = 8; off >= 1; off >>= 1) {
        #pragma unroll
        for (int i = 0; i < 8; ++i) {
            const float ov = __shfl_xor(best[i], off);
            const int   oi = __shfl_xor(besti[i], off);
            if (ov < best[i] || (ov == best[i] && oi < besti[i])) {
                best[i] = ov; besti[i] = oi;
            }
        }
    }
    if (tc == 0) {
        #pragma unroll
        for (int i = 0; i < 8; ++i) {
            const int row = r0 + tr * 8 + i;
            minval[cb * N_ROWS + row] = best[i];
            minidx[cb * N_ROWS + row] = besti[i];
        }
    }
}

// ---------------------------------------------------------------------------
// k3: reduce 8 chunk-minima per row -> final idx; histogram; idx as float out
__global__ __launch_bounds__(256) void reduce_argmin_kernel(
    const float* __restrict__ minval, const int* __restrict__ minidx,
    int* __restrict__ idx_ws, float* __restrict__ out_idx,
    unsigned int* __restrict__ hist)
{
    const int n = blockIdx.x * 256 + threadIdx.x;
    float bv = minval[n];
    int   bi = minidx[n];
    #pragma unroll
    for (int c = 1; c < 8; ++c) {
        const float v = minval[c * N_ROWS + n];
        const int   i = minidx[c * N_ROWS + n];
        if (v < bv || (v == bv && i < bi)) { bv = v; bi = i; }
    }
    idx_ws[n] = bi;
    out_idx[n] = (float)bi;
    atomicAdd(&hist[bi], 1u);
}

// ---------------------------------------------------------------------------
// k4: z_q gather (transposed back to (b,c,h,w)) + fused squared-error sum
__global__ __launch_bounds__(256) void gather_zq_loss_kernel(
    const float* __restrict__ z, const float* __restrict__ emb,
    const int* __restrict__ idx_ws, float* __restrict__ zq_out,
    double* __restrict__ loss_accum)
{
    const int g = blockIdx.x;          // 0..255: 64 rows each
    const int wave = threadIdx.x >> 6;
    const int lane = threadIdx.x & 63;
    const int n = g * 64 + lane;
    const int b = n >> 10;
    const int sp = n & 1023;
    const int code = idx_ws[n];
    const float* erow = emb + (size_t)code * K_DIM;
    const float* zrow = z + (size_t)b * K_DIM * HW + sp;
    float* orow = zq_out + (size_t)b * K_DIM * HW + sp;

    float lsum = 0.0f;
    for (int c = wave; c < K_DIM; c += 4) {
        const float e  = erow[c];
        const float zp = zrow[(size_t)c * HW];
        orow[(size_t)c * HW] = e;
        const float d = e - zp;
        lsum += d * d;
    }
    #pragma unroll
    for (int off = 32; off; off >>= 1) lsum += __shfl_xor(lsum, off);
    __shared__ float wsum[4];
    if (lane == 0) wsum[wave] = lsum;
    __syncthreads();
    if (threadIdx.x == 0)
        atomicAdd(loss_accum, (double)(wsum[0] + wsum[1] + wsum[2] + wsum[3]));
}

// ---------------------------------------------------------------------------
// k5: one-hot fill (1.07 GB of writes; output offset is 8B aligned).
// Write-once stream: nontemporal stores keep it out of L2/LLC.
__global__ __launch_bounds__(256) void onehot_fill_kernel(
    const int* __restrict__ idx_ws, floatx2* __restrict__ out)
{
    const size_t gidx = (size_t)blockIdx.x * 256 + threadIdx.x; // 134217728 total
    const int row = (int)(gidx >> 13);          // 8192 float2 per row
    const int col2 = ((int)gidx & 8191) * 2;
    const int code = idx_ws[row];
    floatx2 v = {0.0f, 0.0f};
    if (code == col2)     v.x = 1.0f;
    if (code == col2 + 1) v.y = 1.0f;
    __builtin_nontemporal_store(v, &out[gidx]);
}

// ---------------------------------------------------------------------------
// k6: scalars: loss = 1.25 * sum / (N*D); perplexity = exp(-sum p log(p+1e-10))
__global__ __launch_bounds__(256) void finalize_scalars_kernel(
    const double* __restrict__ loss_accum, const unsigned int* __restrict__ hist,
    float* __restrict__ out_scalars)
{
    const int tid = threadIdx.x;
    double s = 0.0;
    for (int j = tid; j < N_CODES; j += 256) {
        const double p = (double)hist[j] * (1.0 / (double)N_ROWS);
        s += p * log(p + 1e-10);
    }
    #pragma unroll
    for (int off = 32; off; off >>= 1) s += __shfl_xor(s, off);
    __shared__ double sh[4];
    const int wave = tid >> 6, lane = tid & 63;
    if (lane == 0) sh[wave] = s;
    __syncthreads();
    if (tid == 0) {
        const double S = sh[0] + sh[1] + sh[2] + sh[3];
        out_scalars[0] = (float)(1.25 * loss_accum[0] * (1.0 / (double)N_ELEMS));
        out_scalars[1] = (float)exp(-S);
    }
}

// ---------------------------------------------------------------------------
extern "C" void kernel_launch(void* const* d_in, const int* in_sizes, int n_in,
                              void* d_out, int out_size, void* d_ws, size_t ws_size,
                              hipStream_t stream)
{
    const float* z   = (const float*)d_in[0];
    const float* emb = (const float*)d_in[1];
    float* out = (float*)d_out;
    char* ws = (char*)d_ws;

    double*       loss_accum = (double*)(ws + WS_LOSS);
    unsigned int* hist       = (unsigned int*)(ws + WS_HIST);
    int*          idx_ws     = (int*)(ws + WS_IDX);
    float*        enorm      = (float*)(ws + WS_ENORM);
    float*        minval     = (float*)(ws + WS_MINVAL);
    int*          minidx     = (int*)(ws + WS_MINIDX);
    float*        znorm      = (float*)(ws + WS_ZNORM);

    // zero loss accumulator + histogram (ws is poisoned 0xAA before each call)
    (void)hipMemsetAsync(ws, 0, WS_ENORM, stream);

    znorm_kernel<<<dim3(N_ROWS / 256), dim3(256), 0, stream>>>(z, znorm);
    enorm_kernel<<<dim3(N_CODES / 256), dim3(256), 0, stream>>>(emb, enorm);

    gemm_argmin_kernel<<<dim3(128, 8), dim3(256), 0, stream>>>(
        z, emb, enorm, znorm, minval, minidx);

    reduce_argmin_kernel<<<dim3(N_ROWS / 256), dim3(256), 0, stream>>>(
        minval, minidx, idx_ws, out + OUT_IDX, hist);

    gather_zq_loss_kernel<<<dim3(N_ROWS / 64), dim3(256), 0, stream>>>(
        z, emb, idx_ws, out + OUT_ZQ, loss_accum);

    onehot_fill_kernel<<<dim3(524288), dim3(256), 0, stream>>>(
        idx_ws, (floatx2*)(out + OUT_ONEHOT));

    finalize_scalars_kernel<<<dim3(1), dim3(256), 0, stream>>>(
        loss_accum, hist, out + OUT_LOSS);
}

// Round 5
// 2439.928 us; speedup vs baseline: 1.2149x; 1.2149x over previous
//
#include <hip/hip_runtime.h>
#include <math.h>

// Problem constants
#define N_ROWS   16384   // B*H*W
#define N_CODES  16384   // N_EMBED
#define K_DIM    256     // EMBED_DIM
#define HW       1024    // 32*32
#define N_ELEMS  4194304 // N_ROWS * K_DIM

// Output layout (floats), concatenated in reference return order
#define OUT_ZQ      0
#define OUT_LOSS    4194304
#define OUT_PERP    4194305
#define OUT_ONEHOT  4194306
#define OUT_IDX     272629762   // 4194306 + 16384*16384

// ws layout (bytes) — small scratch only
#define WS_LOSS    0        // double
#define WS_HIST    64       // 16384 u32
#define WS_IDX     65600    // 16384 i32
#define WS_ENORM   131136   // 16384 f32
#define WS_ZNORM   196672   // 16384 f32

// Big scratch lives INSIDE the one-hot output region (1.07 GB), which is
// re-poisoned before every call and fully overwritten by onehot_fill at the
// end. SCB = d_out byte offset 16777232 (16B aligned). Offsets in bytes:
#define SC_ZT    0          // 16 MB  fp32 z transposed [N_ROWS][K_DIM]
#define SC_ZHI   16777216   // 8 MB   bf16 stripe-swizzled
#define SC_ZLO   25165824   // 8 MB
#define SC_EHI   33554432   // 8 MB
#define SC_ELO   41943040   // 8 MB
#define SC_BMIN  50331648   // 8 MB   f32  [N_ROWS][128]
#define SC_BPACK 58720256   // 8 MB   u32  [N_ROWS][128] = (idx<<8)|cnt

#define MARGIN 1.25e-4f

typedef float  floatx2 __attribute__((ext_vector_type(2)));
typedef float  f32x4   __attribute__((ext_vector_type(4)));
typedef short  bf16x8  __attribute__((ext_vector_type(8)));
typedef unsigned short u16x8 __attribute__((ext_vector_type(8)));

__device__ __forceinline__ unsigned short bf16rn(float f) {
    unsigned int x = __float_as_uint(f);
    return (unsigned short)((x + 0x7fffu + ((x >> 16) & 1u)) >> 16);
}

// Stripe-swizzled bf16 layout: stripes of (8 rows x 64 k) = 1024 B, stripe
// index = (row>>3)*4 + (k>>6); within stripe: byte = (row&7)*128 +
// (((k&63)*2) ^ ((row&7)<<4)). This makes ds_read_b128 of MFMA fragments
// ~2-way bank aliased (free) instead of 16-way, while global_load_lds can
// copy stripes verbatim (linear dest + pre-swizzled source, T2/rule 21).

// ---------------------------------------------------------------------------
// convert z: emit zt (fp32 [n][k]) + zhi/zlo (swizzled bf16 split)
__global__ __launch_bounds__(256) void convert_z_kernel(
    const float* __restrict__ z, float* __restrict__ zt,
    unsigned short* __restrict__ zhi, unsigned short* __restrict__ zlo)
{
    const int tid = blockIdx.x * 256 + threadIdx.x;   // 524288 total
    const int n  = tid & 16383;                       // n-fast: coalesced z
    const int kg = tid >> 14;                         // 0..31 (8 k's each)
    const int bimg = n >> 10, sp = n & 1023;
    const float* zp = z + (size_t)bimg * (K_DIM * HW) + (size_t)(kg * 8) * HW + sp;

    float f[8]; u16x8 hv, lv;
    #pragma unroll
    for (int j = 0; j < 8; ++j) f[j] = zp[(size_t)j * HW];
    #pragma unroll
    for (int j = 0; j < 8; ++j) {
        unsigned short h = bf16rn(f[j]);
        float fh = __uint_as_float(((unsigned int)h) << 16);
        hv[j] = h;
        lv[j] = bf16rn(f[j] - fh);
    }
    float4 a = make_float4(f[0], f[1], f[2], f[3]);
    float4 b = make_float4(f[4], f[5], f[6], f[7]);
    *(float4*)(zt + (size_t)n * 256 + kg * 8)     = a;
    *(float4*)(zt + (size_t)n * 256 + kg * 8 + 4) = b;

    const int rs = n >> 3, rowin = n & 7, kc = kg >> 3;
    const size_t stripe = (size_t)(rs * 4 + kc) * 512;  // ushort units
    const int inoff = rowin * 64 + (((((kg & 7) * 16)) ^ (rowin << 4)) >> 1);
    *(u16x8*)(zhi + stripe + inoff) = hv;
    *(u16x8*)(zlo + stripe + inoff) = lv;
}

// convert emb: ehi/elo swizzled bf16 split
__global__ __launch_bounds__(256) void convert_e_kernel(
    const float* __restrict__ emb,
    unsigned short* __restrict__ ehi, unsigned short* __restrict__ elo)
{
    const int tid = blockIdx.x * 256 + threadIdx.x;
    const int kg = tid & 31;                          // kg-fast: coalesced emb
    const int j  = tid >> 5;
    const float* ep = emb + (size_t)j * 256 + kg * 8;
    u16x8 hv, lv;
    #pragma unroll
    for (int t = 0; t < 8; ++t) {
        float f = ep[t];
        unsigned short h = bf16rn(f);
        float fh = __uint_as_float(((unsigned int)h) << 16);
        hv[t] = h;
        lv[t] = bf16rn(f - fh);
    }
    const int rs = j >> 3, rowin = j & 7, kc = kg >> 3;
    const size_t stripe = (size_t)(rs * 4 + kc) * 512;
    const int inoff = rowin * 64 + (((((kg & 7) * 16)) ^ (rowin << 4)) >> 1);
    *(u16x8*)(ehi + stripe + inoff) = hv;
    *(u16x8*)(elo + stripe + inoff) = lv;
}

// ---------------------------------------------------------------------------
// znorm/enorm: numpy-pairwise bit-match (validated round 4)
__global__ __launch_bounds__(256) void znorm_kernel(
    const float* __restrict__ z, float* __restrict__ znorm)
{
    const int n = blockIdx.x * 256 + threadIdx.x;
    const int b = n >> 10;
    const int sp = n & 1023;
    const float* zr = z + (size_t)b * K_DIM * HW + sp;

    float h0, h1;
    {
        float r[8];
        #pragma unroll
        for (int j = 0; j < 8; ++j) {
            float v = zr[(size_t)j * HW];
            float sq = v * v; asm volatile("" : "+v"(sq));
            r[j] = sq;
        }
        for (int i = 8; i < 128; i += 8) {
            #pragma unroll
            for (int j = 0; j < 8; ++j) {
                float v = zr[(size_t)(i + j) * HW];
                float sq = v * v; asm volatile("" : "+v"(sq));
                r[j] += sq;
            }
        }
        h0 = ((r[0] + r[1]) + (r[2] + r[3])) + ((r[4] + r[5]) + (r[6] + r[7]));
    }
    {
        float r[8];
        #pragma unroll
        for (int j = 0; j < 8; ++j) {
            float v = zr[(size_t)(128 + j) * HW];
            float sq = v * v; asm volatile("" : "+v"(sq));
            r[j] = sq;
        }
        for (int i = 8; i < 128; i += 8) {
            #pragma unroll
            for (int j = 0; j < 8; ++j) {
                float v = zr[(size_t)(128 + i + j) * HW];
                float sq = v * v; asm volatile("" : "+v"(sq));
                r[j] += sq;
            }
        }
        h1 = ((r[0] + r[1]) + (r[2] + r[3])) + ((r[4] + r[5]) + (r[6] + r[7]));
    }
    znorm[n] = h0 + h1;
}

__global__ __launch_bounds__(256) void enorm_kernel(
    const float* __restrict__ emb, float* __restrict__ enorm)
{
    const int jc = blockIdx.x * 256 + threadIdx.x;
    const float* er = emb + (size_t)jc * K_DIM;

    float h0, h1;
    {
        float r[8];
        #pragma unroll
        for (int j = 0; j < 8; ++j) {
            float v = er[j];
            float sq = v * v; asm volatile("" : "+v"(sq));
            r[j] = sq;
        }
        for (int i = 8; i < 128; i += 8) {
            #pragma unroll
            for (int j = 0; j < 8; ++j) {
                float v = er[i + j];
                float sq = v * v; asm volatile("" : "+v"(sq));
                r[j] += sq;
            }
        }
        h0 = ((r[0] + r[1]) + (r[2] + r[3])) + ((r[4] + r[5]) + (r[6] + r[7]));
    }
    {
        float r[8];
        #pragma unroll
        for (int j = 0; j < 8; ++j) {
            float v = er[128 + j];
            float sq = v * v; asm volatile("" : "+v"(sq));
            r[j] = sq;
        }
        for (int i = 8; i < 128; i += 8) {
            #pragma unroll
            for (int j = 0; j < 8; ++j) {
                float v = er[128 + i + j];
                float sq = v * v; asm volatile("" : "+v"(sq));
                r[j] += sq;
            }
        }
        h1 = ((r[0] + r[1]) + (r[2] + r[3])) + ((r[4] + r[5]) + (r[6] + r[7]));
    }
    enorm[jc] = h0 + h1;
}

// ---------------------------------------------------------------------------
// Phase A: MFMA filter GEMM over virtual K'=768 (zhi*ehi + zhi*elo + zlo*ehi)
// 128x128 tile, 4 waves (2x2), BK=64. Per (row, col-block): min approx score,
// its argmin, and count of cols within MARGIN of the min.
__global__ __launch_bounds__(256) void mfma_min_kernel(
    const unsigned short* __restrict__ zhi, const unsigned short* __restrict__ zlo,
    const unsigned short* __restrict__ ehi, const unsigned short* __restrict__ elo,
    const float* __restrict__ enorm,
    float* __restrict__ bmin, unsigned int* __restrict__ bpack)
{
    __shared__ unsigned short At[8192];   // 128 x 64 bf16 (swizzled stripes)
    __shared__ unsigned short Bt[8192];

    const int rb = blockIdx.x;            // 0..127 row block
    const int cb = blockIdx.y;            // 0..127 col block
    const int tid = threadIdx.x;
    const int wid = tid >> 6;
    const int lane = tid & 63;
    const int wr = wid >> 1, wc = wid & 1;
    const int l15 = lane & 15, l4 = lane >> 4;

    f32x4 acc[4][4];
    #pragma unroll
    for (int mf = 0; mf < 4; ++mf)
        #pragma unroll
        for (int nf = 0; nf < 4; ++nf)
            acc[mf][nf] = (f32x4){0.f, 0.f, 0.f, 0.f};

    for (int c = 0; c < 12; ++c) {
        const unsigned short* asrc = (c < 8) ? zhi : zlo;
        const unsigned short* bsrc = ((c >> 2) == 1) ? elo : ehi;
        const int kc = c & 3;
        __syncthreads();   // previous compute done before overwrite
        #pragma unroll
        for (int q = 0; q < 4; ++q) {
            const int s = wid * 4 + q;    // stripe 0..15
            const unsigned short* ga = asrc + (size_t)((rb * 16 + s) * 4 + kc) * 512 + lane * 8;
            __builtin_amdgcn_global_load_lds(
                (const __attribute__((address_space(1))) void*)ga,
                (__attribute__((address_space(3))) void*)(At + s * 512), 16, 0, 0);
            const unsigned short* gb = bsrc + (size_t)((cb * 16 + s) * 4 + kc) * 512 + lane * 8;
            __builtin_amdgcn_global_load_lds(
                (const __attribute__((address_space(1))) void*)gb,
                (__attribute__((address_space(3))) void*)(Bt + s * 512), 16, 0, 0);
        }
        __syncthreads();
        #pragma unroll
        for (int sub = 0; sub < 2; ++sub) {
            bf16x8 af[4], bfr[4];
            const int kb = sub * 64 + l4 * 16;   // byte offset of k slice
            #pragma unroll
            for (int mf = 0; mf < 4; ++mf) {
                const int row = wr * 64 + mf * 16 + l15;
                const int off = row * 128 + (kb ^ ((row & 7) << 4));
                af[mf] = *(const bf16x8*)((const char*)At + off);
            }
            #pragma unroll
            for (int nf = 0; nf < 4; ++nf) {
                const int row = wc * 64 + nf * 16 + l15;
                const int off = row * 128 + (kb ^ ((row & 7) << 4));
                bfr[nf] = *(const bf16x8*)((const char*)Bt + off);
            }
            #pragma unroll
            for (int mf = 0; mf < 4; ++mf)
                #pragma unroll
                for (int nf = 0; nf < 4; ++nf)
                    acc[mf][nf] = __builtin_amdgcn_mfma_f32_16x16x32_bf16(
                        af[mf], bfr[nf], acc[mf][nf], 0, 0, 0);
        }
    }
    __syncthreads();

    // epilogue: s~ = enorm - 2*acc; per-row {min, argmin, count<=min+MARGIN}
    float en[4];
    #pragma unroll
    for (int nf = 0; nf < 4; ++nf)
        en[nf] = enorm[cb * 128 + wc * 64 + nf * 16 + l15];

    float* Vh = (float*)&At[0];                 // [2][128]
    unsigned int* Ih = (unsigned int*)&At[512];
    unsigned int* Ch = (unsigned int*)&At[1024];

    #pragma unroll
    for (int mf = 0; mf < 4; ++mf) {
        #pragma unroll
        for (int i = 0; i < 4; ++i) {
            float bv = 3.4e38f; int bc = 0x7fffffff;
            #pragma unroll
            for (int nf = 0; nf < 4; ++nf) {
                const float s = en[nf] - 2.0f * acc[mf][nf][i];
                const int col = cb * 128 + wc * 64 + nf * 16 + l15;
                if (s < bv) { bv = s; bc = col; }   // ascending cols per lane
            }
            #pragma unroll
            for (int off = 1; off < 16; off <<= 1) {
                const float ov = __shfl_xor(bv, off);
                const int oc = __shfl_xor(bc, off);
                if (ov < bv || (ov == bv && oc < bc)) { bv = ov; bc = oc; }
            }
            int cnt = 0;
            #pragma unroll
            for (int nf = 0; nf < 4; ++nf) {
                const float s = en[nf] - 2.0f * acc[mf][nf][i];
                cnt += (s <= bv + MARGIN) ? 1 : 0;
            }
            #pragma unroll
            for (int off = 1; off < 16; off <<= 1) cnt += __shfl_xor(cnt, off);
            if (l15 == 0) {
                const int rr = wr * 64 + mf * 16 + l4 * 4 + i;
                Vh[wc * 128 + rr] = bv;
                Ih[wc * 128 + rr] = (unsigned int)bc;
                Ch[wc * 128 + rr] = (unsigned int)cnt;
            }
        }
    }
    __syncthreads();
    if (tid < 128) {
        const float v0 = Vh[tid], v1 = Vh[128 + tid];
        const unsigned int i0 = Ih[tid], i1 = Ih[128 + tid];
        unsigned int cnt = Ch[tid] + Ch[128 + tid];   // conservative sum
        float v; unsigned int ix;
        if (v1 < v0 || (v1 == v0 && i1 < i0)) { v = v1; ix = i1; }
        else { v = v0; ix = i0; }
        const size_t o = (size_t)(rb * 128 + tid) * 128 + cb;
        bmin[o] = v;
        bpack[o] = (ix << 8) | (cnt > 255u ? 255u : cnt);
    }
}

// ---------------------------------------------------------------------------
// Phase B: wave per row. Global min of 128 block minima; exact rescore of
// candidates (cnt==1 -> stored idx; cnt>=2 -> cooperative full-block scan).
// Exact d = fl(fl(zn+en) - 2*dot), dot = in-order fp32 FMA chain (validated).
__global__ __launch_bounds__(256) void argmin_exact_kernel(
    const float* __restrict__ zt, const float* __restrict__ emb,
    const float* __restrict__ enorm, const float* __restrict__ znorm,
    const float* __restrict__ bmin, const unsigned int* __restrict__ bpack,
    int* __restrict__ idx_ws, float* __restrict__ out_idx,
    unsigned int* __restrict__ hist)
{
    __shared__ float ZL[4][256];
    const int tid = threadIdx.x, wv = tid >> 6, lane = tid & 63;
    const int n = blockIdx.x * 4 + wv;

    *(float4*)&ZL[wv][lane * 4] = ((const float4*)(zt + (size_t)n * 256))[lane];
    __syncthreads();

    const float zn = znorm[n];
    float bd = 3.4e38f; int bi = 0x7fffffff;

    const float m0 = bmin[(size_t)n * 128 + lane];
    const float m1 = bmin[(size_t)n * 128 + 64 + lane];
    float g = fminf(m0, m1);
    #pragma unroll
    for (int off = 1; off < 64; off <<= 1) g = fminf(g, __shfl_xor(g, off));
    const float thr = g + MARGIN;

    #pragma unroll
    for (int half = 0; half < 2; ++half) {
        const float bm = half ? m1 : m0;
        const int c = half * 64 + lane;
        const unsigned int pk = bpack[(size_t)n * 128 + c];
        const int cnt = (int)(pk & 255u);
        const int cand = (int)(pk >> 8);
        const bool act = (bm <= thr);
        if (act && cnt == 1) {
            const float* er = emb + (size_t)cand * 256;
            float dot = 0.f;
            for (int k = 0; k < 256; ++k) dot += ZL[wv][k] * er[k];
            const float t1 = zn + enorm[cand];
            const float d = t1 - 2.0f * dot;
            if (d < bd || (d == bd && cand < bi)) { bd = d; bi = cand; }
        }
        unsigned long long need = __ballot(act && cnt > 1);
        while (need) {
            const int c2 = __ffsll((unsigned long long)need) - 1;
            need &= need - 1;
            const int base = (half * 64 + c2) * 128;
            #pragma unroll
            for (int t = 0; t < 2; ++t) {
                const int j = base + t * 64 + lane;
                const float* er = emb + (size_t)j * 256;
                float dot = 0.f;
                for (int k = 0; k < 256; ++k) dot += ZL[wv][k] * er[k];
                const float t1 = zn + enorm[j];
                const float d = t1 - 2.0f * dot;
                if (d < bd || (d == bd && j < bi)) { bd = d; bi = j; }
            }
        }
    }
    #pragma unroll
    for (int off = 1; off < 64; off <<= 1) {
        const float od = __shfl_xor(bd, off);
        const int oi = __shfl_xor(bi, off);
        if (od < bd || (od == bd && oi < bi)) { bd = od; bi = oi; }
    }
    if (lane == 0) {
        idx_ws[n] = bi;
        out_idx[n] = (float)bi;
        atomicAdd(&hist[bi], 1u);
    }
}

// ---------------------------------------------------------------------------
// z_q gather + fused squared-error sum (validated round 4)
__global__ __launch_bounds__(256) void gather_zq_loss_kernel(
    const float* __restrict__ z, const float* __restrict__ emb,
    const int* __restrict__ idx_ws, float* __restrict__ zq_out,
    double* __restrict__ loss_accum)
{
    const int g = blockIdx.x;
    const int wave = threadIdx.x >> 6;
    const int lane = threadIdx.x & 63;
    const int n = g * 64 + lane;
    const int b = n >> 10;
    const int sp = n & 1023;
    const int code = idx_ws[n];
    const float* erow = emb + (size_t)code * K_DIM;
    const float* zrow = z + (size_t)b * K_DIM * HW + sp;
    float* orow = zq_out + (size_t)b * K_DIM * HW + sp;

    float lsum = 0.0f;
    for (int c = wave; c < K_DIM; c += 4) {
        const float e  = erow[c];
        const float zp = zrow[(size_t)c * HW];
        orow[(size_t)c * HW] = e;
        const float d = e - zp;
        lsum += d * d;
    }
    #pragma unroll
    for (int off = 32; off; off >>= 1) lsum += __shfl_xor(lsum, off);
    __shared__ float wsum[4];
    if (lane == 0) wsum[wave] = lsum;
    __syncthreads();
    if (threadIdx.x == 0)
        atomicAdd(loss_accum, (double)(wsum[0] + wsum[1] + wsum[2] + wsum[3]));
}

// ---------------------------------------------------------------------------
// one-hot fill, aligned: row base is 8 mod 16 -> head float2, float4 body,
// tail float2; nontemporal (write-once 1.07 GB). Also overwrites all scratch.
__global__ __launch_bounds__(256) void onehot_fill_kernel(
    const int* __restrict__ idx_ws, float* __restrict__ out)  // out = +OUT_ONEHOT
{
    const int r = blockIdx.x;
    const int code = idx_ws[r];
    float* row = out + (size_t)r * 16384;
    for (int s = threadIdx.x; s < 4096; s += 256) {
        if (s == 0) {
            floatx2 h = {code == 0 ? 1.f : 0.f, code == 1 ? 1.f : 0.f};
            __builtin_nontemporal_store(h, (floatx2*)row);
        }
        if (s < 4095) {
            const int cc = 2 + s * 4;
            f32x4 v = {code == cc ? 1.f : 0.f, code == cc + 1 ? 1.f : 0.f,
                       code == cc + 2 ? 1.f : 0.f, code == cc + 3 ? 1.f : 0.f};
            __builtin_nontemporal_store(v, (f32x4*)(row + cc));
        } else {
            floatx2 tpair = {code == 16382 ? 1.f : 0.f, code == 16383 ? 1.f : 0.f};
            __builtin_nontemporal_store(tpair, (floatx2*)(row + 16382));
        }
    }
}

// ---------------------------------------------------------------------------
__global__ __launch_bounds__(1024) void finalize_scalars_kernel(
    const double* __restrict__ loss_accum, const unsigned int* __restrict__ hist,
    float* __restrict__ out_scalars)
{
    const int tid = threadIdx.x;
    double s = 0.0;
    for (int j = tid; j < N_CODES; j += 1024) {
        const double p = (double)hist[j] * (1.0 / (double)N_ROWS);
        s += p * log(p + 1e-10);
    }
    #pragma unroll
    for (int off = 32; off; off >>= 1) s += __shfl_xor(s, off);
    __shared__ double sh[16];
    const int wave = tid >> 6, lane = tid & 63;
    if (lane == 0) sh[wave] = s;
    __syncthreads();
    if (tid == 0) {
        double S = 0.0;
        for (int w = 0; w < 16; ++w) S += sh[w];
        out_scalars[0] = (float)(1.25 * loss_accum[0] * (1.0 / (double)N_ELEMS));
        out_scalars[1] = (float)exp(-S);
    }
}

// ---------------------------------------------------------------------------
extern "C" void kernel_launch(void* const* d_in, const int* in_sizes, int n_in,
                              void* d_out, int out_size, void* d_ws, size_t ws_size,
                              hipStream_t stream)
{
    const float* z   = (const float*)d_in[0];
    const float* emb = (const float*)d_in[1];
    float* out = (float*)d_out;
    char* ws = (char*)d_ws;

    double*       loss_accum = (double*)(ws + WS_LOSS);
    unsigned int* hist       = (unsigned int*)(ws + WS_HIST);
    int*          idx_ws     = (int*)(ws + WS_IDX);
    float*        enorm      = (float*)(ws + WS_ENORM);
    float*        znorm      = (float*)(ws + WS_ZNORM);

    char* scb = (char*)(out + OUT_ONEHOT) + 8;   // 16B-aligned scratch base
    float*          zt    = (float*)(scb + SC_ZT);
    unsigned short* zhi   = (unsigned short*)(scb + SC_ZHI);
    unsigned short* zlo   = (unsigned short*)(scb + SC_ZLO);
    unsigned short* ehi   = (unsigned short*)(scb + SC_EHI);
    unsigned short* elo   = (unsigned short*)(scb + SC_ELO);
    float*          bminp = (float*)(scb + SC_BMIN);
    unsigned int*   bpack = (unsigned int*)(scb + SC_BPACK);

    (void)hipMemsetAsync(ws, 0, WS_ENORM, stream);   // loss + hist (+idx)

    convert_z_kernel<<<dim3(2048), dim3(256), 0, stream>>>(z, zt, zhi, zlo);
    convert_e_kernel<<<dim3(2048), dim3(256), 0, stream>>>(emb, ehi, elo);
    znorm_kernel<<<dim3(N_ROWS / 256), dim3(256), 0, stream>>>(z, znorm);
    enorm_kernel<<<dim3(N_CODES / 256), dim3(256), 0, stream>>>(emb, enorm);

    mfma_min_kernel<<<dim3(128, 128), dim3(256), 0, stream>>>(
        zhi, zlo, ehi, elo, enorm, bminp, bpack);

    argmin_exact_kernel<<<dim3(N_ROWS / 4), dim3(256), 0, stream>>>(
        zt, emb, enorm, znorm, bminp, bpack, idx_ws, out + OUT_IDX, hist);

    gather_zq_loss_kernel<<<dim3(N_ROWS / 64), dim3(256), 0, stream>>>(
        z, emb, idx_ws, out + OUT_ZQ, loss_accum);

    onehot_fill_kernel<<<dim3(16384), dim3(256), 0, stream>>>(
        idx_ws, out + OUT_ONEHOT);

    finalize_scalars_kernel<<<dim3(1), dim3(1024), 0, stream>>>(
        loss_accum, hist, out + OUT_LOSS);
}

// Round 6
// 1979.426 us; speedup vs baseline: 1.4975x; 1.2326x over previous
//
#include <hip/hip_runtime.h>
#include <math.h>

// Problem constants
#define N_ROWS   16384   // B*H*W
#define N_CODES  16384   // N_EMBED
#define K_DIM    256     // EMBED_DIM
#define HW       1024    // 32*32
#define N_ELEMS  4194304 // N_ROWS * K_DIM

// Output layout (floats), concatenated in reference return order
#define OUT_ZQ      0
#define OUT_LOSS    4194304
#define OUT_PERP    4194305
#define OUT_ONEHOT  4194306
#define OUT_IDX     272629762   // 4194306 + 16384*16384

// ws layout (bytes) — small scratch only
#define WS_LOSS    0        // double
#define WS_HIST    64       // 16384 u32
#define WS_IDX     65600    // 16384 i32
#define WS_ENORM   131136   // 16384 f32
#define WS_ZNORM   196672   // 16384 f32

// Big scratch INSIDE the one-hot output region (re-poisoned every call,
// fully overwritten by onehot_fill at the end). SCB = d_out + OUT_ONEHOT + 8
// floats? no: byte offset 8 past OUT_ONEHOT start -> 16B aligned.
#define SC_ZT    0          // 16 MB  fp32 z transposed [N_ROWS][K_DIM]
#define SC_ZHI   16777216   // 8 MB   bf16 stripe-swizzled
#define SC_ZLO   25165824   // 8 MB
#define SC_EHI   33554432   // 8 MB
#define SC_BMIN  41943040   // 8 MB   f32  [N_ROWS][128]
#define SC_BPACK 50331648   // 8 MB   u32  [N_ROWS][128] = (idx<<8)|cnt

// Filter margin: must cover 2*(ref fp32 quant-slop ~3.1e-5 + filter error:
// dropped z*elo <= 256*1.2e-7 = 3.07e-5 worst-case + split/mfma rounding).
// 2e-4 gives ~54% headroom; expected extra candidates/row ~0.8.
#define MARGIN 2.0e-4f

typedef float  floatx2 __attribute__((ext_vector_type(2)));
typedef float  f32x4   __attribute__((ext_vector_type(4)));
typedef short  bf16x8  __attribute__((ext_vector_type(8)));
typedef unsigned short u16x8 __attribute__((ext_vector_type(8)));

__device__ __forceinline__ unsigned short bf16rn(float f) {
    unsigned int x = __float_as_uint(f);
    return (unsigned short)((x + 0x7fffu + ((x >> 16) & 1u)) >> 16);
}

// Stripe-swizzled bf16 layout (validated R5): stripes of (8 rows x 64 k) =
// 1024 B; stripe id = (row>>3)*4 + (k>>6); within stripe byte =
// (row&7)*128 + (((k&63)*2) ^ ((row&7)<<4)). ds_read_b128 of MFMA fragments
// is ~2-way bank aliased (free); global_load_lds copies stripes verbatim.

// ---------------------------------------------------------------------------
// convert z: emit zt (fp32 [n][k]) + zhi/zlo (swizzled bf16 split)
__global__ __launch_bounds__(256) void convert_z_kernel(
    const float* __restrict__ z, float* __restrict__ zt,
    unsigned short* __restrict__ zhi, unsigned short* __restrict__ zlo)
{
    const int tid = blockIdx.x * 256 + threadIdx.x;   // 524288 total
    const int n  = tid & 16383;                       // n-fast: coalesced z
    const int kg = tid >> 14;                         // 0..31 (8 k's each)
    const int bimg = n >> 10, sp = n & 1023;
    const float* zp = z + (size_t)bimg * (K_DIM * HW) + (size_t)(kg * 8) * HW + sp;

    float f[8]; u16x8 hv, lv;
    #pragma unroll
    for (int j = 0; j < 8; ++j) f[j] = zp[(size_t)j * HW];
    #pragma unroll
    for (int j = 0; j < 8; ++j) {
        unsigned short h = bf16rn(f[j]);
        float fh = __uint_as_float(((unsigned int)h) << 16);
        hv[j] = h;
        lv[j] = bf16rn(f[j] - fh);
    }
    float4 a = make_float4(f[0], f[1], f[2], f[3]);
    float4 b = make_float4(f[4], f[5], f[6], f[7]);
    *(float4*)(zt + (size_t)n * 256 + kg * 8)     = a;
    *(float4*)(zt + (size_t)n * 256 + kg * 8 + 4) = b;

    const int rs = n >> 3, rowin = n & 7, kc = kg >> 3;
    const size_t stripe = (size_t)(rs * 4 + kc) * 512;  // ushort units
    const int inoff = rowin * 64 + (((((kg & 7) * 16)) ^ (rowin << 4)) >> 1);
    *(u16x8*)(zhi + stripe + inoff) = hv;
    *(u16x8*)(zlo + stripe + inoff) = lv;
}

// convert emb: ehi only (elo product dropped; covered by MARGIN)
__global__ __launch_bounds__(256) void convert_e_kernel(
    const float* __restrict__ emb, unsigned short* __restrict__ ehi)
{
    const int tid = blockIdx.x * 256 + threadIdx.x;
    const int kg = tid & 31;                          // kg-fast: coalesced emb
    const int j  = tid >> 5;
    const float* ep = emb + (size_t)j * 256 + kg * 8;
    u16x8 hv;
    #pragma unroll
    for (int t = 0; t < 8; ++t) hv[t] = bf16rn(ep[t]);
    const int rs = j >> 3, rowin = j & 7, kc = kg >> 3;
    const size_t stripe = (size_t)(rs * 4 + kc) * 512;
    const int inoff = rowin * 64 + (((((kg & 7) * 16)) ^ (rowin << 4)) >> 1);
    *(u16x8*)(ehi + stripe + inoff) = hv;
}

// ---------------------------------------------------------------------------
// znorm/enorm: numpy-pairwise bit-match (validated round 4)
__global__ __launch_bounds__(256) void znorm_kernel(
    const float* __restrict__ z, float* __restrict__ znorm)
{
    const int n = blockIdx.x * 256 + threadIdx.x;
    const int b = n >> 10;
    const int sp = n & 1023;
    const float* zr = z + (size_t)b * K_DIM * HW + sp;

    float h0, h1;
    {
        float r[8];
        #pragma unroll
        for (int j = 0; j < 8; ++j) {
            float v = zr[(size_t)j * HW];
            float sq = v * v; asm volatile("" : "+v"(sq));
            r[j] = sq;
        }
        for (int i = 8; i < 128; i += 8) {
            #pragma unroll
            for (int j = 0; j < 8; ++j) {
                float v = zr[(size_t)(i + j) * HW];
                float sq = v * v; asm volatile("" : "+v"(sq));
                r[j] += sq;
            }
        }
        h0 = ((r[0] + r[1]) + (r[2] + r[3])) + ((r[4] + r[5]) + (r[6] + r[7]));
    }
    {
        float r[8];
        #pragma unroll
        for (int j = 0; j < 8; ++j) {
            float v = zr[(size_t)(128 + j) * HW];
            float sq = v * v; asm volatile("" : "+v"(sq));
            r[j] = sq;
        }
        for (int i = 8; i < 128; i += 8) {
            #pragma unroll
            for (int j = 0; j < 8; ++j) {
                float v = zr[(size_t)(128 + i + j) * HW];
                float sq = v * v; asm volatile("" : "+v"(sq));
                r[j] += sq;
            }
        }
        h1 = ((r[0] + r[1]) + (r[2] + r[3])) + ((r[4] + r[5]) + (r[6] + r[7]));
    }
    znorm[n] = h0 + h1;
}

__global__ __launch_bounds__(256) void enorm_kernel(
    const float* __restrict__ emb, float* __restrict__ enorm)
{
    const int jc = blockIdx.x * 256 + threadIdx.x;
    const float* er = emb + (size_t)jc * K_DIM;

    float h0, h1;
    {
        float r[8];
        #pragma unroll
        for (int j = 0; j < 8; ++j) {
            float v = er[j];
            float sq = v * v; asm volatile("" : "+v"(sq));
            r[j] = sq;
        }
        for (int i = 8; i < 128; i += 8) {
            #pragma unroll
            for (int j = 0; j < 8; ++j) {
                float v = er[i + j];
                float sq = v * v; asm volatile("" : "+v"(sq));
                r[j] += sq;
            }
        }
        h0 = ((r[0] + r[1]) + (r[2] + r[3])) + ((r[4] + r[5]) + (r[6] + r[7]));
    }
    {
        float r[8];
        #pragma unroll
        for (int j = 0; j < 8; ++j) {
            float v = er[128 + j];
            float sq = v * v; asm volatile("" : "+v"(sq));
            r[j] = sq;
        }
        for (int i = 8; i < 128; i += 8) {
            #pragma unroll
            for (int j = 0; j < 8; ++j) {
                float v = er[128 + i + j];
                float sq = v * v; asm volatile("" : "+v"(sq));
                r[j] += sq;
            }
        }
        h1 = ((r[0] + r[1]) + (r[2] + r[3])) + ((r[4] + r[5]) + (r[6] + r[7]));
    }
    enorm[jc] = h0 + h1;
}

// ---------------------------------------------------------------------------
// Phase A: MFMA filter, virtual K'=512 ((zhi||zlo) x ehi), 256x128 tile,
// 8 waves (4x2), B panel resident in LDS (64KB, staged once, contiguous in
// global), A chunks (32KB) double-buffered. 128KB LDS -> 1 block/CU.
// Epilogue: per (row, col-block) {block min, block argmin, count of cols
// within MARGIN of the BLOCK min}.
__global__ __launch_bounds__(512) void mfma_min_kernel(
    const unsigned short* __restrict__ zhi, const unsigned short* __restrict__ zlo,
    const unsigned short* __restrict__ ehi, const float* __restrict__ enorm,
    float* __restrict__ bmin, unsigned int* __restrict__ bpack)
{
    __shared__ unsigned short Bs[32768];      // 64KB: ehi 128 codes x 256 k
    __shared__ unsigned short As[2][16384];   // 2x32KB: 256 rows x 64 k

    const int rb = blockIdx.x;    // 0..63  (256-row tile)
    const int cb = blockIdx.y;    // 0..127 (128-code block)
    const int tid = threadIdx.x;
    const int wid = tid >> 6;     // 0..7
    const int lane = tid & 63;
    const int wr = wid >> 1;      // 0..3 row quadrant (64 rows)
    const int wc = wid & 1;       // 0..1 col half (64 cols)
    const int l15 = lane & 15, l4 = lane >> 4;

    // stage B panel once: global stripes cb*64..cb*64+63 are contiguous 64KB
    {
        const unsigned short* gb = ehi + (size_t)cb * 32768 + wid * 512 + lane * 8;
        #pragma unroll
        for (int i = 0; i < 8; ++i)
            __builtin_amdgcn_global_load_lds(
                (const __attribute__((address_space(1))) void*)(gb + i * 4096),
                (__attribute__((address_space(3))) void*)(Bs + i * 4096 + wid * 512),
                16, 0, 0);
    }
    // stage A chunk kc of asrc into As[b]
    const size_t abase = (size_t)rb * 128 * 512;   // stripe (rb*32)*4, ushorts
    auto stageA = [&](const unsigned short* asrc, int kc, int b) {
        #pragma unroll
        for (int i = 0; i < 4; ++i) {
            const int s = i * 8 + wid;             // row-stripe 0..31
            const unsigned short* ga = asrc + abase + (size_t)kc * 512
                                       + (size_t)s * 2048 + lane * 8;
            __builtin_amdgcn_global_load_lds(
                (const __attribute__((address_space(1))) void*)ga,
                (__attribute__((address_space(3))) void*)(&As[b][s * 512]),
                16, 0, 0);
        }
    };

    f32x4 acc[4][4];
    #pragma unroll
    for (int mf = 0; mf < 4; ++mf)
        #pragma unroll
        for (int nf = 0; nf < 4; ++nf)
            acc[mf][nf] = (f32x4){0.f, 0.f, 0.f, 0.f};

    stageA(zhi, 0, 0);
    __syncthreads();   // compiler drains vmcnt before barrier

    for (int c = 0; c < 8; ++c) {
        const int cur = c & 1;
        if (c < 7) {
            const unsigned short* nsrc = (c + 1 < 4) ? zhi : zlo;
            stageA(nsrc, (c + 1) & 3, cur ^ 1);
        }
        const int kc = c & 3;
        #pragma unroll
        for (int sub = 0; sub < 2; ++sub) {
            bf16x8 af[4], bfr[4];
            const int kb = sub * 64 + l4 * 16;     // byte slice within row
            #pragma unroll
            for (int mf = 0; mf < 4; ++mf) {
                const int row = wr * 64 + mf * 16 + l15;
                const int off = row * 128 + (kb ^ ((row & 7) << 4));
                af[mf] = *(const bf16x8*)((const char*)&As[cur][0] + off);
            }
            #pragma unroll
            for (int nf = 0; nf < 4; ++nf) {
                const int crow = wc * 64 + nf * 16 + l15;
                const int off = ((crow >> 3) * 4 + kc) * 1024
                              + (crow & 7) * 128 + (kb ^ ((crow & 7) << 4));
                bfr[nf] = *(const bf16x8*)((const char*)Bs + off);
            }
            #pragma unroll
            for (int mf = 0; mf < 4; ++mf)
                #pragma unroll
                for (int nf = 0; nf < 4; ++nf)
                    acc[mf][nf] = __builtin_amdgcn_mfma_f32_16x16x32_bf16(
                        af[mf], bfr[nf], acc[mf][nf], 0, 0, 0);
        }
        __syncthreads();   // reads done before buffer overwrite; prefetch drains
    }

    // ---- epilogue: s~ = enorm - 2*acc (znorm omitted: constant per row) ----
    float en[4];
    #pragma unroll
    for (int nf = 0; nf < 4; ++nf)
        en[nf] = enorm[cb * 128 + wc * 64 + nf * 16 + l15];

    float*        Vh = (float*)&As[0][0];          // [2][256]
    unsigned int* Ih = (unsigned int*)(Vh + 512);  // [2][256]
    unsigned int* Ch = (unsigned int*)(Ih + 512);  // [2][256]
    float*        Gm = (float*)(Ch + 512);         // [256] block-min bcast

    // pass 1: per-row min+argmin within this wave's 64-col half
    #pragma unroll
    for (int mf = 0; mf < 4; ++mf) {
        #pragma unroll
        for (int i = 0; i < 4; ++i) {
            float bv = 3.4e38f; int bc = 0x7fffffff;
            #pragma unroll
            for (int nf = 0; nf < 4; ++nf) {
                const float s = en[nf] - 2.0f * acc[mf][nf][i];
                const int col = cb * 128 + wc * 64 + nf * 16 + l15;
                if (s < bv) { bv = s; bc = col; }   // ascending cols per lane
            }
            #pragma unroll
            for (int off = 1; off < 16; off <<= 1) {
                const float ov = __shfl_xor(bv, off);
                const int oc = __shfl_xor(bc, off);
                if (ov < bv || (ov == bv && oc < bc)) { bv = ov; bc = oc; }
            }
            if (l15 == 0) {
                const int rr = wr * 64 + mf * 16 + l4 * 4 + i;
                Vh[wc * 256 + rr] = bv;
                Ih[wc * 256 + rr] = (unsigned int)bc;
            }
        }
    }
    __syncthreads();
    if (tid < 256) {
        const float v0 = Vh[tid], v1 = Vh[256 + tid];
        const unsigned int i0 = Ih[tid], i1 = Ih[256 + tid];
        float v; unsigned int ix;
        if (v1 < v0 || (v1 == v0 && i1 < i0)) { v = v1; ix = i1; }
        else { v = v0; ix = i0; }
        Gm[tid] = v;
        Vh[tid] = v;
        Ih[tid] = ix;
    }
    __syncthreads();
    // pass 2: count cols within MARGIN of the BLOCK min (cnt==1 => the block
    // argmin is the unique candidate; phase B rescores just it)
    #pragma unroll
    for (int mf = 0; mf < 4; ++mf) {
        #pragma unroll
        for (int i = 0; i < 4; ++i) {
            const int rr = wr * 64 + mf * 16 + l4 * 4 + i;
            const float thr = Gm[rr] + MARGIN;
            int cnt = 0;
            #pragma unroll
            for (int nf = 0; nf < 4; ++nf)
                cnt += (en[nf] - 2.0f * acc[mf][nf][i] <= thr) ? 1 : 0;
            #pragma unroll
            for (int off = 1; off < 16; off <<= 1) cnt += __shfl_xor(cnt, off);
            if (l15 == 0) Ch[wc * 256 + rr] = (unsigned int)cnt;
        }
    }
    __syncthreads();
    if (tid < 256) {
        unsigned int cnt = Ch[tid] + Ch[256 + tid];
        const size_t o = (size_t)(rb * 256 + tid) * 128 + cb;
        bmin[o] = Vh[tid];
        bpack[o] = (Ih[tid] << 8) | (cnt > 255u ? 255u : cnt);
    }
}

// ---------------------------------------------------------------------------
// Phase B: wave per row. Global min over 128 block minima; candidates =
// blocks with bm <= gmin+MARGIN. cnt==1 -> exact-rescore stored block argmin;
// cnt>=2 -> cooperative exact full-block scan. Exact d = fl(fl(zn+en)-2*dot),
// dot = in-order fp32 FMA chain (bitwise-matches reference; validated R4).
__global__ __launch_bounds__(256) void argmin_exact_kernel(
    const float* __restrict__ zt, const float* __restrict__ emb,
    const float* __restrict__ enorm, const float* __restrict__ znorm,
    const float* __restrict__ bmin, const unsigned int* __restrict__ bpack,
    int* __restrict__ idx_ws, float* __restrict__ out_idx,
    unsigned int* __restrict__ hist)
{
    __shared__ float ZL[4][256];
    const int tid = threadIdx.x, wv = tid >> 6, lane = tid & 63;
    const int n = blockIdx.x * 4 + wv;

    *(float4*)&ZL[wv][lane * 4] = ((const float4*)(zt + (size_t)n * 256))[lane];
    __syncthreads();

    const float zn = znorm[n];
    float bd = 3.4e38f; int bi = 0x7fffffff;

    const float m0 = bmin[(size_t)n * 128 + lane];
    const float m1 = bmin[(size_t)n * 128 + 64 + lane];
    float g = fminf(m0, m1);
    #pragma unroll
    for (int off = 1; off < 64; off <<= 1) g = fminf(g, __shfl_xor(g, off));
    const float thr = g + MARGIN;

    #pragma unroll
    for (int half = 0; half < 2; ++half) {
        const float bm = half ? m1 : m0;
        const unsigned int pk = bpack[(size_t)n * 128 + half * 64 + lane];
        const int cnt = (int)(pk & 255u);
        const int cand = (int)(pk >> 8);
        const bool act = (bm <= thr);
        if (act && cnt == 1) {
            const float* er = emb + (size_t)cand * 256;
            float dot = 0.f;
            for (int k = 0; k < 256; ++k) dot += ZL[wv][k] * er[k];
            const float t1 = zn + enorm[cand];
            const float d = t1 - 2.0f * dot;
            if (d < bd || (d == bd && cand < bi)) { bd = d; bi = cand; }
        }
        unsigned long long need = __ballot(act && cnt > 1);
        while (need) {
            const int c2 = __ffsll((unsigned long long)need) - 1;
            need &= need - 1;
            const int base = (half * 64 + c2) * 128;
            #pragma unroll
            for (int t = 0; t < 2; ++t) {
                const int j = base + t * 64 + lane;
                const float* er = emb + (size_t)j * 256;
                float dot = 0.f;
                for (int k = 0; k < 256; ++k) dot += ZL[wv][k] * er[k];
                const float t1 = zn + enorm[j];
                const float d = t1 - 2.0f * dot;
                if (d < bd || (d == bd && j < bi)) { bd = d; bi = j; }
            }
        }
    }
    #pragma unroll
    for (int off = 1; off < 64; off <<= 1) {
        const float od = __shfl_xor(bd, off);
        const int oi = __shfl_xor(bi, off);
        if (od < bd || (od == bd && oi < bi)) { bd = od; bi = oi; }
    }
    if (lane == 0) {
        idx_ws[n] = bi;
        out_idx[n] = (float)bi;
        atomicAdd(&hist[bi], 1u);
    }
}

// ---------------------------------------------------------------------------
// z_q gather + fused squared-error sum (validated round 4)
__global__ __launch_bounds__(256) void gather_zq_loss_kernel(
    const float* __restrict__ z, const float* __restrict__ emb,
    const int* __restrict__ idx_ws, float* __restrict__ zq_out,
    double* __restrict__ loss_accum)
{
    const int g = blockIdx.x;
    const int wave = threadIdx.x >> 6;
    const int lane = threadIdx.x & 63;
    const int n = g * 64 + lane;
    const int b = n >> 10;
    const int sp = n & 1023;
    const int code = idx_ws[n];
    const float* erow = emb + (size_t)code * K_DIM;
    const float* zrow = z + (size_t)b * K_DIM * HW + sp;
    float* orow = zq_out + (size_t)b * K_DIM * HW + sp;

    float lsum = 0.0f;
    for (int c = wave; c < K_DIM; c += 4) {
        const float e  = erow[c];
        const float zp = zrow[(size_t)c * HW];
        orow[(size_t)c * HW] = e;
        const float d = e - zp;
        lsum += d * d;
    }
    #pragma unroll
    for (int off = 32; off; off >>= 1) lsum += __shfl_xor(lsum, off);
    __shared__ float wsum[4];
    if (lane == 0) wsum[wave] = lsum;
    __syncthreads();
    if (threadIdx.x == 0)
        atomicAdd(loss_accum, (double)(wsum[0] + wsum[1] + wsum[2] + wsum[3]));
}

// ---------------------------------------------------------------------------
// one-hot fill: head float2, float4 body, tail float2; nontemporal stores
// (write-once 1.07 GB). Also overwrites all scratch in the output region.
__global__ __launch_bounds__(256) void onehot_fill_kernel(
    const int* __restrict__ idx_ws, float* __restrict__ out)  // +OUT_ONEHOT
{
    const int r = blockIdx.x;
    const int code = idx_ws[r];
    float* row = out + (size_t)r * 16384;
    for (int s = threadIdx.x; s < 4096; s += 256) {
        if (s == 0) {
            floatx2 h = {code == 0 ? 1.f : 0.f, code == 1 ? 1.f : 0.f};
            __builtin_nontemporal_store(h, (floatx2*)row);
        }
        if (s < 4095) {
            const int cc = 2 + s * 4;
            f32x4 v = {code == cc ? 1.f : 0.f, code == cc + 1 ? 1.f : 0.f,
                       code == cc + 2 ? 1.f : 0.f, code == cc + 3 ? 1.f : 0.f};
            __builtin_nontemporal_store(v, (f32x4*)(row + cc));
        } else {
            floatx2 tpair = {code == 16382 ? 1.f : 0.f, code == 16383 ? 1.f : 0.f};
            __builtin_nontemporal_store(tpair, (floatx2*)(row + 16382));
        }
    }
}

// ---------------------------------------------------------------------------
__global__ __launch_bounds__(1024) void finalize_scalars_kernel(
    const double* __restrict__ loss_accum, const unsigned int* __restrict__ hist,
    float* __restrict__ out_scalars)
{
    const int tid = threadIdx.x;
    double s = 0.0;
    for (int j = tid; j < N_CODES; j += 1024) {
        const double p = (double)hist[j] * (1.0 / (double)N_ROWS);
        s += p * log(p + 1e-10);
    }
    #pragma unroll
    for (int off = 32; off; off >>= 1) s += __shfl_xor(s, off);
    __shared__ double sh[16];
    const int wave = tid >> 6, lane = tid & 63;
    if (lane == 0) sh[wave] = s;
    __syncthreads();
    if (tid == 0) {
        double S = 0.0;
        for (int w = 0; w < 16; ++w) S += sh[w];
        out_scalars[0] = (float)(1.25 * loss_accum[0] * (1.0 / (double)N_ELEMS));
        out_scalars[1] = (float)exp(-S);
    }
}

// ---------------------------------------------------------------------------
extern "C" void kernel_launch(void* const* d_in, const int* in_sizes, int n_in,
                              void* d_out, int out_size, void* d_ws, size_t ws_size,
                              hipStream_t stream)
{
    const float* z   = (const float*)d_in[0];
    const float* emb = (const float*)d_in[1];
    float* out = (float*)d_out;
    char* ws = (char*)d_ws;

    double*       loss_accum = (double*)(ws + WS_LOSS);
    unsigned int* hist       = (unsigned int*)(ws + WS_HIST);
    int*          idx_ws     = (int*)(ws + WS_IDX);
    float*        enorm      = (float*)(ws + WS_ENORM);
    float*        znorm      = (float*)(ws + WS_ZNORM);

    char* scb = (char*)(out + OUT_ONEHOT) + 8;   // 16B-aligned scratch base
    float*          zt    = (float*)(scb + SC_ZT);
    unsigned short* zhi   = (unsigned short*)(scb + SC_ZHI);
    unsigned short* zlo   = (unsigned short*)(scb + SC_ZLO);
    unsigned short* ehi   = (unsigned short*)(scb + SC_EHI);
    float*          bminp = (float*)(scb + SC_BMIN);
    unsigned int*   bpack = (unsigned int*)(scb + SC_BPACK);

    (void)hipMemsetAsync(ws, 0, WS_ENORM, stream);   // loss + hist (+idx)

    convert_z_kernel<<<dim3(2048), dim3(256), 0, stream>>>(z, zt, zhi, zlo);
    convert_e_kernel<<<dim3(2048), dim3(256), 0, stream>>>(emb, ehi);
    znorm_kernel<<<dim3(N_ROWS / 256), dim3(256), 0, stream>>>(z, znorm);
    enorm_kernel<<<dim3(N_CODES / 256), dim3(256), 0, stream>>>(emb, enorm);

    mfma_min_kernel<<<dim3(64, 128), dim3(512), 0, stream>>>(
        zhi, zlo, ehi, enorm, bminp, bpack);

    argmin_exact_kernel<<<dim3(N_ROWS / 4), dim3(256), 0, stream>>>(
        zt, emb, enorm, znorm, bminp, bpack, idx_ws, out + OUT_IDX, hist);

    gather_zq_loss_kernel<<<dim3(N_ROWS / 64), dim3(256), 0, stream>>>(
        z, emb, idx_ws, out + OUT_ZQ, loss_accum);

    onehot_fill_kernel<<<dim3(16384), dim3(256), 0, stream>>>(
        idx_ws, out + OUT_ONEHOT);

    finalize_scalars_kernel<<<dim3(1), dim3(1024), 0, stream>>>(
        loss_accum, hist, out + OUT_LOSS);
}

// Round 7
// 1761.019 us; speedup vs baseline: 1.6832x; 1.1240x over previous
//
#include <hip/hip_runtime.h>
#include <math.h>

// Problem constants
#define N_ROWS   16384   // B*H*W
#define N_CODES  16384   // N_EMBED
#define K_DIM    256     // EMBED_DIM
#define HW       1024    // 32*32
#define N_ELEMS  4194304 // N_ROWS * K_DIM

// Output layout (floats), concatenated in reference return order
#define OUT_ZQ      0
#define OUT_LOSS    4194304
#define OUT_PERP    4194305
#define OUT_ONEHOT  4194306
#define OUT_IDX     272629762   // 4194306 + 16384*16384

// ws layout (bytes) — small scratch only
#define WS_LOSS    0        // double
#define WS_HIST    64       // 16384 u32
#define WS_IDX     65600    // 16384 i32
#define WS_ENORM   131136   // 16384 f32
#define WS_ZNORM   196672   // 16384 f32

// Big scratch INSIDE the one-hot output region (re-poisoned every call,
// fully overwritten by onehot_fill at the end). scb = d_out+OUT_ONEHOT+8B.
#define SC_ZT    0          // 16 MB  fp32 z transposed [N_ROWS][K_DIM]
#define SC_ZHI   16777216   // 8 MB   bf16 stripe-swizzled
#define SC_EHI   33554432   // 8 MB   bf16 stripe-swizzled
#define SC_BMIN  41943040   // 8 MB   f32  [N_ROWS][128]
#define SC_BPACK 50331648   // 8 MB   u32  [N_ROWS][128] = (idx<<8)|cnt

// Filter margin. Pure-bf16 filter (zhi x ehi): dropped terms zlo*ehi + z*elo
// have per-row std ~1e-6 (|e| <= 1/16384!). Need MARGIN >= 2E + quant-slop
// (~6e-5). 4e-4 is >100 sigma of headroom; ~3-5 candidates/row get exact
// rescoring in phase B (bitwise reference argmin, validated R4-R6).
#define MARGIN 4.0e-4f

typedef float  floatx2 __attribute__((ext_vector_type(2)));
typedef float  f32x4   __attribute__((ext_vector_type(4)));
typedef short  bf16x8  __attribute__((ext_vector_type(8)));
typedef unsigned short u16x8 __attribute__((ext_vector_type(8)));

__device__ __forceinline__ unsigned short bf16rn(float f) {
    unsigned int x = __float_as_uint(f);
    return (unsigned short)((x + 0x7fffu + ((x >> 16) & 1u)) >> 16);
}

// Stripe-swizzled bf16 layout (validated R5/R6): stripes of (8 rows x 64 k)
// = 1024 B; stripe id = (row>>3)*4 + (k>>6); within stripe, ushort offset =
// (row&7)*64 + ((k&63) ^ ((row&7)<<3)). ds_read_b128 of MFMA fragments is
// conflict-free (measured 0); stripes are verbatim-copyable (linear).

// ---------------------------------------------------------------------------
// convert z: emit zt (fp32 [n][k]) + zhi (swizzled bf16)
__global__ __launch_bounds__(256) void convert_z_kernel(
    const float* __restrict__ z, float* __restrict__ zt,
    unsigned short* __restrict__ zhi)
{
    const int tid = blockIdx.x * 256 + threadIdx.x;   // 524288 total
    const int n  = tid & 16383;                       // n-fast: coalesced z
    const int kg = tid >> 14;                         // 0..31 (8 k's each)
    const int bimg = n >> 10, sp = n & 1023;
    const float* zp = z + (size_t)bimg * (K_DIM * HW) + (size_t)(kg * 8) * HW + sp;

    float f[8]; u16x8 hv;
    #pragma unroll
    for (int j = 0; j < 8; ++j) f[j] = zp[(size_t)j * HW];
    #pragma unroll
    for (int j = 0; j < 8; ++j) hv[j] = bf16rn(f[j]);

    float4 a = make_float4(f[0], f[1], f[2], f[3]);
    float4 b = make_float4(f[4], f[5], f[6], f[7]);
    *(float4*)(zt + (size_t)n * 256 + kg * 8)     = a;
    *(float4*)(zt + (size_t)n * 256 + kg * 8 + 4) = b;

    const int rs = n >> 3, rowin = n & 7, kc = kg >> 3;
    const size_t stripe = (size_t)(rs * 4 + kc) * 512;  // ushort units
    const int inoff = rowin * 64 + ((((kg & 7) * 8)) ^ (rowin << 3));
    *(u16x8*)(zhi + stripe + inoff) = hv;
}

// convert emb: ehi (swizzled bf16)
__global__ __launch_bounds__(256) void convert_e_kernel(
    const float* __restrict__ emb, unsigned short* __restrict__ ehi)
{
    const int tid = blockIdx.x * 256 + threadIdx.x;
    const int kg = tid & 31;                          // kg-fast: coalesced emb
    const int j  = tid >> 5;
    const float* ep = emb + (size_t)j * 256 + kg * 8;
    u16x8 hv;
    #pragma unroll
    for (int t = 0; t < 8; ++t) hv[t] = bf16rn(ep[t]);
    const int rs = j >> 3, rowin = j & 7, kc = kg >> 3;
    const size_t stripe = (size_t)(rs * 4 + kc) * 512;
    const int inoff = rowin * 64 + ((((kg & 7) * 8)) ^ (rowin << 3));
    *(u16x8*)(ehi + stripe + inoff) = hv;
}

// ---------------------------------------------------------------------------
// znorm/enorm: numpy-pairwise bit-match (validated round 4)
__global__ __launch_bounds__(256) void znorm_kernel(
    const float* __restrict__ z, float* __restrict__ znorm)
{
    const int n = blockIdx.x * 256 + threadIdx.x;
    const int b = n >> 10;
    const int sp = n & 1023;
    const float* zr = z + (size_t)b * K_DIM * HW + sp;

    float h0, h1;
    {
        float r[8];
        #pragma unroll
        for (int j = 0; j < 8; ++j) {
            float v = zr[(size_t)j * HW];
            float sq = v * v; asm volatile("" : "+v"(sq));
            r[j] = sq;
        }
        for (int i = 8; i < 128; i += 8) {
            #pragma unroll
            for (int j = 0; j < 8; ++j) {
                float v = zr[(size_t)(i + j) * HW];
                float sq = v * v; asm volatile("" : "+v"(sq));
                r[j] += sq;
            }
        }
        h0 = ((r[0] + r[1]) + (r[2] + r[3])) + ((r[4] + r[5]) + (r[6] + r[7]));
    }
    {
        float r[8];
        #pragma unroll
        for (int j = 0; j < 8; ++j) {
            float v = zr[(size_t)(128 + j) * HW];
            float sq = v * v; asm volatile("" : "+v"(sq));
            r[j] = sq;
        }
        for (int i = 8; i < 128; i += 8) {
            #pragma unroll
            for (int j = 0; j < 8; ++j) {
                float v = zr[(size_t)(128 + i + j) * HW];
                float sq = v * v; asm volatile("" : "+v"(sq));
                r[j] += sq;
            }
        }
        h1 = ((r[0] + r[1]) + (r[2] + r[3])) + ((r[4] + r[5]) + (r[6] + r[7]));
    }
    znorm[n] = h0 + h1;
}

__global__ __launch_bounds__(256) void enorm_kernel(
    const float* __restrict__ emb, float* __restrict__ enorm)
{
    const int jc = blockIdx.x * 256 + threadIdx.x;
    const float* er = emb + (size_t)jc * K_DIM;

    float h0, h1;
    {
        float r[8];
        #pragma unroll
        for (int j = 0; j < 8; ++j) {
            float v = er[j];
            float sq = v * v; asm volatile("" : "+v"(sq));
            r[j] = sq;
        }
        for (int i = 8; i < 128; i += 8) {
            #pragma unroll
            for (int j = 0; j < 8; ++j) {
                float v = er[i + j];
                float sq = v * v; asm volatile("" : "+v"(sq));
                r[j] += sq;
            }
        }
        h0 = ((r[0] + r[1]) + (r[2] + r[3])) + ((r[4] + r[5]) + (r[6] + r[7]));
    }
    {
        float r[8];
        #pragma unroll
        for (int j = 0; j < 8; ++j) {
            float v = er[128 + j];
            float sq = v * v; asm volatile("" : "+v"(sq));
            r[j] = sq;
        }
        for (int i = 8; i < 128; i += 8) {
            #pragma unroll
            for (int j = 0; j < 8; ++j) {
                float v = er[128 + i + j];
                float sq = v * v; asm volatile("" : "+v"(sq));
                r[j] += sq;
            }
        }
        h1 = ((r[0] + r[1]) + (r[2] + r[3])) + ((r[4] + r[5]) + (r[6] + r[7]));
    }
    enorm[jc] = h0 + h1;
}

// ---------------------------------------------------------------------------
// Phase A: pure-bf16 MFMA filter, K=256. Tile 256 rows x 128 codes, 8 waves
// (4x2). B panel (128 codes x 256 k = 64KB) resident in LDS, staged once.
// A fragments read DIRECTLY from global (L2-resident; each wave's 4 frags =
// one contiguous 2KB stripe pair) -> ZERO barriers in the K-loop.
// 64KB LDS + ~100 VGPR -> 2 blocks/CU (16 waves): TLP hides load latency.
__global__ __launch_bounds__(512, 4) void mfma_min_kernel(
    const unsigned short* __restrict__ zhi, const unsigned short* __restrict__ ehi,
    const float* __restrict__ enorm,
    float* __restrict__ bmin, unsigned int* __restrict__ bpack)
{
    __shared__ unsigned short Bs[32768];      // 64KB (reused by epilogue)

    const int cb = blockIdx.x;    // 0..127 code block (fast: A stays L2-hot)
    const int rb = blockIdx.y;    // 0..63  row tile
    const int tid = threadIdx.x;
    const int wid = tid >> 6;     // 0..7
    const int lane = tid & 63;
    const int wr = wid >> 1;      // 0..3 row quadrant (64 rows)
    const int wc = wid & 1;       // 0..1 col half (64 cols)
    const int l15 = lane & 15, l4 = lane >> 4;

    // stage B panel once: stripes cb*64.. are a contiguous 64KB in global
    {
        const unsigned short* gb = ehi + (size_t)cb * 32768 + wid * 512 + lane * 8;
        #pragma unroll
        for (int i = 0; i < 8; ++i)
            __builtin_amdgcn_global_load_lds(
                (const __attribute__((address_space(1))) void*)(gb + i * 4096),
                (__attribute__((address_space(3))) void*)(Bs + i * 4096 + wid * 512),
                16, 0, 0);
    }

    // per-mf A base offsets (ushort units) for even/odd 32-k steps
    int pe[4], po[4];
    #pragma unroll
    for (int mf = 0; mf < 4; ++mf) {
        const int r = rb * 256 + wr * 64 + mf * 16 + l15;
        const int x = (r & 7) << 3;
        const int srow = (r >> 3) * 2048 + (r & 7) * 64;
        pe[mf] = srow + ((l4 * 8) ^ x);
        po[mf] = srow + ((32 + l4 * 8) ^ x);
    }
    // per-nf B base offsets within LDS
    int qe[4], qo[4];
    #pragma unroll
    for (int nf = 0; nf < 4; ++nf) {
        const int crow = wc * 64 + nf * 16 + l15;
        const int x = (crow & 7) << 3;
        const int srow = (crow >> 3) * 2048 + (crow & 7) * 64;
        qe[nf] = srow + ((l4 * 8) ^ x);
        qo[nf] = srow + ((32 + l4 * 8) ^ x);
    }

    f32x4 acc[4][4];
    #pragma unroll
    for (int mf = 0; mf < 4; ++mf)
        #pragma unroll
        for (int nf = 0; nf < 4; ++nf)
            acc[mf][nf] = (f32x4){0.f, 0.f, 0.f, 0.f};

    __syncthreads();   // B ready (compiler drains vmcnt)

    for (int t = 0; t < 4; ++t) {           // 4 stripe-chunks of K=64
        const int d = t * 512;
        bf16x8 a[4];
        // even 32-k step
        #pragma unroll
        for (int mf = 0; mf < 4; ++mf)
            a[mf] = *(const bf16x8*)(zhi + (size_t)(pe[mf] + d));
        #pragma unroll
        for (int nf = 0; nf < 4; ++nf) {
            const bf16x8 b = *(const bf16x8*)(Bs + qe[nf] + d);
            #pragma unroll
            for (int mf = 0; mf < 4; ++mf)
                acc[mf][nf] = __builtin_amdgcn_mfma_f32_16x16x32_bf16(
                    a[mf], b, acc[mf][nf], 0, 0, 0);
        }
        // odd 32-k step
        #pragma unroll
        for (int mf = 0; mf < 4; ++mf)
            a[mf] = *(const bf16x8*)(zhi + (size_t)(po[mf] + d));
        #pragma unroll
        for (int nf = 0; nf < 4; ++nf) {
            const bf16x8 b = *(const bf16x8*)(Bs + qo[nf] + d);
            #pragma unroll
            for (int mf = 0; mf < 4; ++mf)
                acc[mf][nf] = __builtin_amdgcn_mfma_f32_16x16x32_bf16(
                    a[mf], b, acc[mf][nf], 0, 0, 0);
        }
    }
    __syncthreads();   // all B reads done before LDS reuse

    // ---- epilogue: s~ = enorm - 2*acc; per (row, col-block) {min, argmin,
    // count within MARGIN of BLOCK min} (validated R6) ----
    float en[4];
    #pragma unroll
    for (int nf = 0; nf < 4; ++nf)
        en[nf] = enorm[cb * 128 + wc * 64 + nf * 16 + l15];

    float*        Vh = (float*)&Bs[0];             // [2][256]
    unsigned int* Ih = (unsigned int*)(Vh + 512);  // [2][256]
    unsigned int* Ch = (unsigned int*)(Ih + 512);  // [2][256]
    float*        Gm = (float*)(Ch + 512);         // [256]

    #pragma unroll
    for (int mf = 0; mf < 4; ++mf) {
        #pragma unroll
        for (int i = 0; i < 4; ++i) {
            float bv = 3.4e38f; int bc = 0x7fffffff;
            #pragma unroll
            for (int nf = 0; nf < 4; ++nf) {
                const float s = en[nf] - 2.0f * acc[mf][nf][i];
                const int col = cb * 128 + wc * 64 + nf * 16 + l15;
                if (s < bv) { bv = s; bc = col; }   // ascending cols per lane
            }
            #pragma unroll
            for (int off = 1; off < 16; off <<= 1) {
                const float ov = __shfl_xor(bv, off);
                const int oc = __shfl_xor(bc, off);
                if (ov < bv || (ov == bv && oc < bc)) { bv = ov; bc = oc; }
            }
            if (l15 == 0) {
                const int rr = wr * 64 + mf * 16 + l4 * 4 + i;
                Vh[wc * 256 + rr] = bv;
                Ih[wc * 256 + rr] = (unsigned int)bc;
            }
        }
    }
    __syncthreads();
    if (tid < 256) {
        const float v0 = Vh[tid], v1 = Vh[256 + tid];
        const unsigned int i0 = Ih[tid], i1 = Ih[256 + tid];
        float v; unsigned int ix;
        if (v1 < v0 || (v1 == v0 && i1 < i0)) { v = v1; ix = i1; }
        else { v = v0; ix = i0; }
        Gm[tid] = v;
        Vh[tid] = v;
        Ih[tid] = ix;
    }
    __syncthreads();
    #pragma unroll
    for (int mf = 0; mf < 4; ++mf) {
        #pragma unroll
        for (int i = 0; i < 4; ++i) {
            const int rr = wr * 64 + mf * 16 + l4 * 4 + i;
            const float thr = Gm[rr] + MARGIN;
            int cnt = 0;
            #pragma unroll
            for (int nf = 0; nf < 4; ++nf)
                cnt += (en[nf] - 2.0f * acc[mf][nf][i] <= thr) ? 1 : 0;
            #pragma unroll
            for (int off = 1; off < 16; off <<= 1) cnt += __shfl_xor(cnt, off);
            if (l15 == 0) Ch[wc * 256 + rr] = (unsigned int)cnt;
        }
    }
    __syncthreads();
    if (tid < 256) {
        unsigned int cnt = Ch[tid] + Ch[256 + tid];
        const size_t o = (size_t)(rb * 256 + tid) * 128 + cb;
        bmin[o] = Vh[tid];
        bpack[o] = (Ih[tid] << 8) | (cnt > 255u ? 255u : cnt);
    }
}

// ---------------------------------------------------------------------------
// Phase B: wave per row; exact rescoring of candidates (bitwise reference
// argmin incl. ties; validated R4-R6).
__global__ __launch_bounds__(256) void argmin_exact_kernel(
    const float* __restrict__ zt, const float* __restrict__ emb,
    const float* __restrict__ enorm, const float* __restrict__ znorm,
    const float* __restrict__ bmin, const unsigned int* __restrict__ bpack,
    int* __restrict__ idx_ws, float* __restrict__ out_idx,
    unsigned int* __restrict__ hist)
{
    __shared__ float ZL[4][256];
    const int tid = threadIdx.x, wv = tid >> 6, lane = tid & 63;
    const int n = blockIdx.x * 4 + wv;

    *(float4*)&ZL[wv][lane * 4] = ((const float4*)(zt + (size_t)n * 256))[lane];
    __syncthreads();

    const float zn = znorm[n];
    float bd = 3.4e38f; int bi = 0x7fffffff;

    const float m0 = bmin[(size_t)n * 128 + lane];
    const float m1 = bmin[(size_t)n * 128 + 64 + lane];
    float g = fminf(m0, m1);
    #pragma unroll
    for (int off = 1; off < 64; off <<= 1) g = fminf(g, __shfl_xor(g, off));
    const float thr = g + MARGIN;

    #pragma unroll
    for (int half = 0; half < 2; ++half) {
        const float bm = half ? m1 : m0;
        const unsigned int pk = bpack[(size_t)n * 128 + half * 64 + lane];
        const int cnt = (int)(pk & 255u);
        const int cand = (int)(pk >> 8);
        const bool act = (bm <= thr);
        if (act && cnt == 1) {
            const float* er = emb + (size_t)cand * 256;
            float dot = 0.f;
            for (int k = 0; k < 256; ++k) dot += ZL[wv][k] * er[k];
            const float t1 = zn + enorm[cand];
            const float d = t1 - 2.0f * dot;
            if (d < bd || (d == bd && cand < bi)) { bd = d; bi = cand; }
        }
        unsigned long long need = __ballot(act && cnt > 1);
        while (need) {
            const int c2 = __ffsll((unsigned long long)need) - 1;
            need &= need - 1;
            const int base = (half * 64 + c2) * 128;
            #pragma unroll
            for (int t = 0; t < 2; ++t) {
                const int j = base + t * 64 + lane;
                const float* er = emb + (size_t)j * 256;
                float dot = 0.f;
                for (int k = 0; k < 256; ++k) dot += ZL[wv][k] * er[k];
                const float t1 = zn + enorm[j];
                const float d = t1 - 2.0f * dot;
                if (d < bd || (d == bd && j < bi)) { bd = d; bi = j; }
            }
        }
    }
    #pragma unroll
    for (int off = 1; off < 64; off <<= 1) {
        const float od = __shfl_xor(bd, off);
        const int oi = __shfl_xor(bi, off);
        if (od < bd || (od == bd && oi < bi)) { bd = od; bi = oi; }
    }
    if (lane == 0) {
        idx_ws[n] = bi;
        out_idx[n] = (float)bi;
        atomicAdd(&hist[bi], 1u);
    }
}

// ---------------------------------------------------------------------------
// z_q gather + fused squared-error sum (validated round 4)
__global__ __launch_bounds__(256) void gather_zq_loss_kernel(
    const float* __restrict__ z, const float* __restrict__ emb,
    const int* __restrict__ idx_ws, float* __restrict__ zq_out,
    double* __restrict__ loss_accum)
{
    const int g = blockIdx.x;
    const int wave = threadIdx.x >> 6;
    const int lane = threadIdx.x & 63;
    const int n = g * 64 + lane;
    const int b = n >> 10;
    const int sp = n & 1023;
    const int code = idx_ws[n];
    const float* erow = emb + (size_t)code * K_DIM;
    const float* zrow = z + (size_t)b * K_DIM * HW + sp;
    float* orow = zq_out + (size_t)b * K_DIM * HW + sp;

    float lsum = 0.0f;
    for (int c = wave; c < K_DIM; c += 4) {
        const float e  = erow[c];
        const float zp = zrow[(size_t)c * HW];
        orow[(size_t)c * HW] = e;
        const float d = e - zp;
        lsum += d * d;
    }
    #pragma unroll
    for (int off = 32; off; off >>= 1) lsum += __shfl_xor(lsum, off);
    __shared__ float wsum[4];
    if (lane == 0) wsum[wave] = lsum;
    __syncthreads();
    if (threadIdx.x == 0)
        atomicAdd(loss_accum, (double)(wsum[0] + wsum[1] + wsum[2] + wsum[3]));
}

// ---------------------------------------------------------------------------
// one-hot fill: head float2, float4 body, tail float2; nontemporal stores
// (write-once 1.07 GB). Also overwrites all scratch in the output region.
__global__ __launch_bounds__(256) void onehot_fill_kernel(
    const int* __restrict__ idx_ws, float* __restrict__ out)  // +OUT_ONEHOT
{
    const int r = blockIdx.x;
    const int code = idx_ws[r];
    float* row = out + (size_t)r * 16384;
    for (int s = threadIdx.x; s < 4096; s += 256) {
        if (s == 0) {
            floatx2 h = {code == 0 ? 1.f : 0.f, code == 1 ? 1.f : 0.f};
            __builtin_nontemporal_store(h, (floatx2*)row);
        }
        if (s < 4095) {
            const int cc = 2 + s * 4;
            f32x4 v = {code == cc ? 1.f : 0.f, code == cc + 1 ? 1.f : 0.f,
                       code == cc + 2 ? 1.f : 0.f, code == cc + 3 ? 1.f : 0.f};
            __builtin_nontemporal_store(v, (f32x4*)(row + cc));
        } else {
            floatx2 tpair = {code == 16382 ? 1.f : 0.f, code == 16383 ? 1.f : 0.f};
            __builtin_nontemporal_store(tpair, (floatx2*)(row + 16382));
        }
    }
}

// ---------------------------------------------------------------------------
__global__ __launch_bounds__(1024) void finalize_scalars_kernel(
    const double* __restrict__ loss_accum, const unsigned int* __restrict__ hist,
    float* __restrict__ out_scalars)
{
    const int tid = threadIdx.x;
    double s = 0.0;
    for (int j = tid; j < N_CODES; j += 1024) {
        const double p = (double)hist[j] * (1.0 / (double)N_ROWS);
        s += p * log(p + 1e-10);
    }
    #pragma unroll
    for (int off = 32; off; off >>= 1) s += __shfl_xor(s, off);
    __shared__ double sh[16];
    const int wave = tid >> 6, lane = tid & 63;
    if (lane == 0) sh[wave] = s;
    __syncthreads();
    if (tid == 0) {
        double S = 0.0;
        for (int w = 0; w < 16; ++w) S += sh[w];
        out_scalars[0] = (float)(1.25 * loss_accum[0] * (1.0 / (double)N_ELEMS));
        out_scalars[1] = (float)exp(-S);
    }
}

// ---------------------------------------------------------------------------
extern "C" void kernel_launch(void* const* d_in, const int* in_sizes, int n_in,
                              void* d_out, int out_size, void* d_ws, size_t ws_size,
                              hipStream_t stream)
{
    const float* z   = (const float*)d_in[0];
    const float* emb = (const float*)d_in[1];
    float* out = (float*)d_out;
    char* ws = (char*)d_ws;

    double*       loss_accum = (double*)(ws + WS_LOSS);
    unsigned int* hist       = (unsigned int*)(ws + WS_HIST);
    int*          idx_ws     = (int*)(ws + WS_IDX);
    float*        enorm      = (float*)(ws + WS_ENORM);
    float*        znorm      = (float*)(ws + WS_ZNORM);

    char* scb = (char*)(out + OUT_ONEHOT) + 8;   // 16B-aligned scratch base
    float*          zt    = (float*)(scb + SC_ZT);
    unsigned short* zhi   = (unsigned short*)(scb + SC_ZHI);
    unsigned short* ehi   = (unsigned short*)(scb + SC_EHI);
    float*          bminp = (float*)(scb + SC_BMIN);
    unsigned int*   bpack = (unsigned int*)(scb + SC_BPACK);

    (void)hipMemsetAsync(ws, 0, WS_ENORM, stream);   // loss + hist (+idx)

    convert_z_kernel<<<dim3(2048), dim3(256), 0, stream>>>(z, zt, zhi);
    convert_e_kernel<<<dim3(2048), dim3(256), 0, stream>>>(emb, ehi);
    znorm_kernel<<<dim3(N_ROWS / 256), dim3(256), 0, stream>>>(z, znorm);
    enorm_kernel<<<dim3(N_CODES / 256), dim3(256), 0, stream>>>(emb, enorm);

    // grid: cb fastest so co-resident blocks share A slices (L2-hot zhi)
    mfma_min_kernel<<<dim3(128, 64), dim3(512), 0, stream>>>(
        zhi, ehi, enorm, bminp, bpack);

    argmin_exact_kernel<<<dim3(N_ROWS / 4), dim3(256), 0, stream>>>(
        zt, emb, enorm, znorm, bminp, bpack, idx_ws, out + OUT_IDX, hist);

    gather_zq_loss_kernel<<<dim3(N_ROWS / 64), dim3(256), 0, stream>>>(
        z, emb, idx_ws, out + OUT_ZQ, loss_accum);

    onehot_fill_kernel<<<dim3(16384), dim3(256), 0, stream>>>(
        idx_ws, out + OUT_ONEHOT);

    finalize_scalars_kernel<<<dim3(1), dim3(1024), 0, stream>>>(
        loss_accum, hist, out + OUT_LOSS);
}